// Round 10
// baseline (359.245 us; speedup 1.0000x reference)
//
#include <hip/hip_runtime.h>
#include <hip/hip_bf16.h>
#include <hip/hip_fp16.h>
#include <math.h>

// ---------------------------------------------------------------------------
// GCN forward on MI355X. fp16 gather tables + fp16 MFMA GEMMs (fp32 accum).
// Structure (R5): aggregate FIRST (linear), GEMM after.
// R9: dispatch-chain compression 13 -> 8 (gaps ~8us each dominate):
//   k_aggemm0 = agg0+gemm0 (agg to LDS, MFMA from LDS, W via L1)
//   k_aggemm1 = prep1+agg1+gemm1 (BN+ReLU+dinv applied inline at gather)
//   k_poolmlp = pool+head (1 block/graph, no atomics)
//   scan_b folded into scan_c (per-block prefix over raw block sums)
// Lessons: R2 unroll-spill; R5 gather=past-L2-BW-bound; R6 MFMA;
//   R7 W-stage-once + A-direct; R8 fuse small kernels, inline bnfinal.
// ---------------------------------------------------------------------------

typedef _Float16 f16x8 __attribute__((ext_vector_type(8)));
typedef float f32x4 __attribute__((ext_vector_type(4)));

__device__ inline unsigned pack2(float a, float b) {
  union { __half2 h; unsigned u; } p;
  p.h = __floats2half2_rn(a, b);
  return p.u;
}
__device__ inline float2 unpack2(unsigned u) {
  union { unsigned u; __half2 h; } p;
  p.u = u;
  return __half22float2(p.h);
}

// ---- setup: deg=1 / bnstat=0 + encoder fold + W1 transpose + gstart ----
__global__ __launch_bounds__(256) void k_setup(
    int* __restrict__ deg, float* __restrict__ bnstat, int statTotal,
    int N, int nbN,
    const float* __restrict__ W_enc, const float* __restrict__ b_enc,
    const float* __restrict__ Wc, unsigned short* __restrict__ MT,
    float* __restrict__ bfold, int NL,
    const float* __restrict__ Wc1, unsigned short* __restrict__ WT1,
    const int* __restrict__ batch, int* __restrict__ gstart) {
  int b = blockIdx.x;
  if (b < nbN) {                       // init
    int i = b * 256 + threadIdx.x;
    if (i < N) deg[i] = 1;             // self-loop
    if (i < statTotal) bnstat[i] = 0.f;
    return;
  }
  b -= nbN;
  if (b < 65) {                        // fold: MT[n][k] fp16, bfold
    if (threadIdx.x < 128) {
      int n = threadIdx.x;
      int k = b;
      const float* arow = (k < 64) ? (W_enc + (size_t)k * 128) : b_enc;
      float acc = 0.f;
      for (int j = 0; j < 128; j++)
        acc = fmaf(arow[j], Wc[(size_t)j * 128 + n], acc);
      if (k < 64) ((__half*)MT)[(size_t)n * 64 + k] = __float2half(acc);
      else bfold[n] = acc;
    }
    return;
  }
  b -= 65;
  if (b < 64) {                        // wprep for layer 1
    if (NL > 1) {
      int i = b * 256 + threadIdx.x;   // 16384
      int n = i & 127, k = i >> 7;
      ((__half*)WT1)[(size_t)n * 128 + k] = __float2half(Wc1[i]);
    }
    return;
  }
  int g = threadIdx.x;                 // gstart (last block)
  if (g <= 64) {
    int lo = 0, hi = N;
    while (lo < hi) {
      int mid = (lo + hi) >> 1;
      if (batch[mid] < g) lo = mid + 1;
      else hi = mid;
    }
    gstart[g] = lo;
  }
}

__global__ __launch_bounds__(256) void k_deg(const int* __restrict__ ei, int E,
                                             int* __restrict__ deg) {
  int i = blockIdx.x * 256 + threadIdx.x;
  if (i < E) atomicAdd(&deg[ei[E + i]], 1);   // dst row
}

// ---- scan: block-local exclusive + raw block totals ----
__global__ __launch_bounds__(256) void k_scan_a(const int* __restrict__ deg, int N,
                                                int* __restrict__ rowptr,
                                                int* __restrict__ blksum) {
  __shared__ int s[256];
  int t = threadIdx.x;
  int i = blockIdx.x * 256 + t;
  int v = (i < N) ? deg[i] : 0;
  s[t] = v;
  __syncthreads();
  for (int off = 1; off < 256; off <<= 1) {
    int x = (t >= off) ? s[t - off] : 0;
    __syncthreads();
    s[t] += x;
    __syncthreads();
  }
  if (i < N) rowptr[i] = s[t] - v;            // exclusive (partial)
  if (t == 255) blksum[blockIdx.x] = s[255];  // raw block total
}

// ---- scan_c: per-block prefix over blksum (scan_b fused, R9) ----
__global__ __launch_bounds__(256) void k_scan_c(const int* __restrict__ deg, int N,
                                                int total,
                                                const int* __restrict__ blksum,
                                                int* __restrict__ rowptr,
                                                int* __restrict__ cursor,
                                                float* __restrict__ dinv) {
  __shared__ int red[256];
  int t = threadIdx.x, b = blockIdx.x;
  int acc = 0;
  for (int j = t; j < b; j += 256) acc += blksum[j];
  red[t] = acc;
  __syncthreads();
  for (int off = 128; off > 0; off >>= 1) {
    if (t < off) red[t] += red[t + off];
    __syncthreads();
  }
  int prefix = red[0];
  int i = b * 256 + t;
  if (i < N) {
    int rp = rowptr[i] + prefix;
    rowptr[i] = rp;
    cursor[i] = rp;
    dinv[i] = rsqrtf((float)deg[i]);
  } else if (i == N) {
    rowptr[N] = total;
  }
}

// ---- CSR fill + prep0 (xs fp16 = x*dinv) in one dispatch ----
__global__ __launch_bounds__(256) void k_fillprep(
    const int* __restrict__ ei, int E, int N, int nbEN,
    int* __restrict__ cursor, int* __restrict__ colx,
    const float* __restrict__ x, const float* __restrict__ dinv,
    unsigned* __restrict__ xs2) {
  int b = blockIdx.x;
  if (b < nbEN) {
    int i = b * 256 + threadIdx.x;
    if (i < E) {
      int s = ei[i];
      int d = ei[E + i];
      int pos = atomicAdd(&cursor[d], 1);
      colx[pos] = s;
    } else if (i < E + N) {
      int j = i - E;
      int pos = atomicAdd(&cursor[j], 1);
      colx[pos] = j;                   // self-loop entry
    }
    return;
  }
  b -= nbEN;
  int i = b * 256 + threadIdx.x;
  if (i < N * 16) {
    int row = i >> 4;
    float4 v = ((const float4*)x)[i];
    float d = dinv[row];
    uint2 o;
    o.x = pack2(v.x * d, v.y * d);
    o.y = pack2(v.z * d, v.w * d);
    ((uint2*)xs2)[i] = o;
  }
}

// ---- fused agg0 + gemm0: block owns 64 rows ----
// Phase 1: quarter-wave/row gather (16 rows/iter x 4 iters) -> LDS Al + wvl.
// Phase 2: MFMA, A-frags from LDS, B-frags from global MT (L1-resident 16KB).
__global__ __launch_bounds__(256, 2) void k_aggemm0(
    const uint2* __restrict__ xs, const int* __restrict__ rowptr,
    const int* __restrict__ colx, const float* __restrict__ dinv,
    const unsigned short* __restrict__ MT,   // 128 x 64 fp16 (n-major)
    const float* __restrict__ bias,          // bc0
    const float* __restrict__ bias2,         // bfold
    float* __restrict__ stat,                // 8 x 256 replicas
    unsigned short* __restrict__ Yh, int N) {
  constexpr int KP = 68;                     // +4 fp16 pad -> 2-way banks
  __shared__ unsigned short Al[64 * KP];
  __shared__ float wvl[64];
  __shared__ float red[4][2][128];

  int lane = threadIdx.x & 63;
  int wv = threadIdx.x >> 6;
  int grp = lane >> 4, l16 = lane & 15;
  int rowBlk = blockIdx.x * 64;

#pragma unroll 1
  for (int it = 0; it < 4; it++) {
    int lr = it * 16 + wv * 4 + grp;
    int i = rowBlk + lr;
    float s0 = 0.f, s1 = 0.f, s2 = 0.f, s3 = 0.f, sd = 0.f;
    if (i < N) {
      int beg = rowptr[i], end = rowptr[i + 1];
      int e = beg;
#pragma unroll 1
      for (; e + 8 <= end; e += 8) {
        int ix[8];
#pragma unroll
        for (int u = 0; u < 8; u++) ix[u] = colx[e + u];
        uint2 v[8];
        float dd[8];
#pragma unroll
        for (int u = 0; u < 8; u++) { v[u] = xs[(size_t)ix[u] * 16 + l16]; dd[u] = dinv[ix[u]]; }
#pragma unroll
        for (int u = 0; u < 8; u++) {
          float2 a = unpack2(v[u].x), b = unpack2(v[u].y);
          s0 += a.x; s1 += a.y; s2 += b.x; s3 += b.y;
          sd += dd[u];
        }
      }
#pragma unroll 1
      for (; e < end; e++) {
        int sr = colx[e];
        uint2 vv = xs[(size_t)sr * 16 + l16];
        float2 a = unpack2(vv.x), b = unpack2(vv.y);
        s0 += a.x; s1 += a.y; s2 += b.x; s3 += b.y;
        sd += dinv[sr];
      }
    }
    float di = (i < N) ? dinv[i] : 0.f;
    *(uint2*)&Al[lr * KP + l16 * 4] =
        make_uint2(pack2(s0 * di, s1 * di), pack2(s2 * di, s3 * di));
    if (l16 == 0) wvl[lr] = di * sd;
  }
  __syncthreads();

  int l15 = lane & 15;
  int kg = lane >> 4;
  f16x8 af[2];
#pragma unroll
  for (int j = 0; j < 2; j++)
    af[j] = *(const f16x8*)&Al[(wv * 16 + l15) * KP + kg * 8 + j * 32];

  f32x4 acc[8];
#pragma unroll
  for (int t = 0; t < 8; t++) acc[t] = {0.f, 0.f, 0.f, 0.f};
#pragma unroll
  for (int j = 0; j < 2; j++) {
#pragma unroll
    for (int t = 0; t < 8; t++) {
      f16x8 bf = *(const f16x8*)&MT[(size_t)(t * 16 + l15) * 64 + kg * 8 + j * 32];
      acc[t] = __builtin_amdgcn_mfma_f32_16x16x32_f16(af[j], bf, acc[t], 0, 0, 0);
    }
  }

  int rbaseL = wv * 16 + kg * 4;
  int rbase = rowBlk + rbaseL;
  float wrow[4];
#pragma unroll
  for (int r = 0; r < 4; r++) wrow[r] = wvl[rbaseL + r];

#pragma unroll
  for (int t = 0; t < 8; t++) {
    int ch = t * 16 + l15;
    float bb = bias[ch];
    float b2v = bias2[ch];
    float s = 0.f, q = 0.f;
#pragma unroll
    for (int r = 0; r < 4; r++) {
      int row = rbase + r;
      if (row < N) {
        float o = fmaf(wrow[r], b2v, acc[t][r] + bb);
        __half oh = __float2half(o);
        Yh[(size_t)row * 128 + ch] = *(unsigned short*)&oh;
        s += o;
        q += o * o;
      }
    }
    s += __shfl_xor(s, 16); s += __shfl_xor(s, 32);
    q += __shfl_xor(q, 16); q += __shfl_xor(q, 32);
    if (kg == 0) { red[wv][0][ch] = s; red[wv][1][ch] = q; }
  }
  __syncthreads();
  int st = threadIdx.x >> 7, ch2 = threadIdx.x & 127;
  float v = red[0][st][ch2] + red[1][st][ch2] + red[2][st][ch2] + red[3][st][ch2];
  atomicAdd(&stat[(blockIdx.x & 7) * 256 + st * 128 + ch2], v);
}

// ---- fused prep1 + agg1 + gemm1: BN+ReLU+dinv applied inline at gather ----
__global__ __launch_bounds__(256, 2) void k_aggemm1(
    const unsigned short* __restrict__ Hprev,  // N x 128 fp16
    const int* __restrict__ rowptr, const int* __restrict__ colx,
    const float* __restrict__ dinv,
    const unsigned short* __restrict__ WT,     // 128 x 128 fp16 (n-major)
    const float* __restrict__ statPrev, const float* __restrict__ gamma,
    const float* __restrict__ beta, float invN,
    const float* __restrict__ bias,            // bc[l]
    float* __restrict__ statCur, unsigned short* __restrict__ Yh, int N) {
  constexpr int KP = 136;                      // +8 fp16 pad -> 2-way banks
  __shared__ unsigned short Al[64 * KP];
  __shared__ float scsh[256];
  __shared__ float red[4][2][128];

  if (threadIdx.x < 128) {
    int c = threadIdx.x;
    float ss = 0.f, qs = 0.f;
#pragma unroll
    for (int r = 0; r < 8; r++) {
      ss += statPrev[r * 256 + c];
      qs += statPrev[r * 256 + 128 + c];
    }
    float mu = ss * invN;
    float var = qs * invN - mu * mu;
    float sc = rsqrtf(var + 1e-5f) * gamma[c];
    scsh[c] = sc;
    scsh[128 + c] = beta[c] - mu * sc;
  }
  __syncthreads();

  int lane = threadIdx.x & 63;
  int wv = threadIdx.x >> 6;
  int half = lane >> 5, l32 = lane & 31;
  int rowBlk = blockIdx.x * 64;
  const uint2* Hp = (const uint2*)Hprev;
  float4 sc = ((const float4*)scsh)[l32];
  float4 sh = ((const float4*)(scsh + 128))[l32];

#pragma unroll 1
  for (int it = 0; it < 8; it++) {
    int lr = it * 8 + wv * 2 + half;
    int i = rowBlk + lr;
    float4 s = make_float4(0.f, 0.f, 0.f, 0.f);
    if (i < N) {
      int beg = rowptr[i], end = rowptr[i + 1];
      int e = beg;
#pragma unroll 1
      for (; e + 4 <= end; e += 4) {
        int i0 = colx[e + 0], i1 = colx[e + 1], i2 = colx[e + 2], i3 = colx[e + 3];
        uint2 v0 = Hp[(size_t)i0 * 32 + l32];
        uint2 v1 = Hp[(size_t)i1 * 32 + l32];
        uint2 v2 = Hp[(size_t)i2 * 32 + l32];
        uint2 v3 = Hp[(size_t)i3 * 32 + l32];
        float d0 = dinv[i0], d1 = dinv[i1], d2 = dinv[i2], d3 = dinv[i3];
        float2 a, b;
        a = unpack2(v0.x); b = unpack2(v0.y);
        s.x += fmaxf(fmaf(a.x, sc.x, sh.x), 0.f) * d0;
        s.y += fmaxf(fmaf(a.y, sc.y, sh.y), 0.f) * d0;
        s.z += fmaxf(fmaf(b.x, sc.z, sh.z), 0.f) * d0;
        s.w += fmaxf(fmaf(b.y, sc.w, sh.w), 0.f) * d0;
        a = unpack2(v1.x); b = unpack2(v1.y);
        s.x += fmaxf(fmaf(a.x, sc.x, sh.x), 0.f) * d1;
        s.y += fmaxf(fmaf(a.y, sc.y, sh.y), 0.f) * d1;
        s.z += fmaxf(fmaf(b.x, sc.z, sh.z), 0.f) * d1;
        s.w += fmaxf(fmaf(b.y, sc.w, sh.w), 0.f) * d1;
        a = unpack2(v2.x); b = unpack2(v2.y);
        s.x += fmaxf(fmaf(a.x, sc.x, sh.x), 0.f) * d2;
        s.y += fmaxf(fmaf(a.y, sc.y, sh.y), 0.f) * d2;
        s.z += fmaxf(fmaf(b.x, sc.z, sh.z), 0.f) * d2;
        s.w += fmaxf(fmaf(b.y, sc.w, sh.w), 0.f) * d2;
        a = unpack2(v3.x); b = unpack2(v3.y);
        s.x += fmaxf(fmaf(a.x, sc.x, sh.x), 0.f) * d3;
        s.y += fmaxf(fmaf(a.y, sc.y, sh.y), 0.f) * d3;
        s.z += fmaxf(fmaf(b.x, sc.z, sh.z), 0.f) * d3;
        s.w += fmaxf(fmaf(b.y, sc.w, sh.w), 0.f) * d3;
      }
#pragma unroll 1
      for (; e < end; e++) {
        int sr = colx[e];
        uint2 vv = Hp[(size_t)sr * 32 + l32];
        float dsr = dinv[sr];
        float2 a = unpack2(vv.x), b = unpack2(vv.y);
        s.x += fmaxf(fmaf(a.x, sc.x, sh.x), 0.f) * dsr;
        s.y += fmaxf(fmaf(a.y, sc.y, sh.y), 0.f) * dsr;
        s.z += fmaxf(fmaf(b.x, sc.z, sh.z), 0.f) * dsr;
        s.w += fmaxf(fmaf(b.y, sc.w, sh.w), 0.f) * dsr;
      }
    }
    float di = (i < N) ? dinv[i] : 0.f;
    *(uint2*)&Al[lr * KP + l32 * 4] =
        make_uint2(pack2(s.x * di, s.y * di), pack2(s.z * di, s.w * di));
  }
  __syncthreads();

  int l15 = lane & 15;
  int kg = lane >> 4;
  f16x8 af[4];
#pragma unroll
  for (int j = 0; j < 4; j++)
    af[j] = *(const f16x8*)&Al[(wv * 16 + l15) * KP + kg * 8 + j * 32];

  f32x4 acc[8];
#pragma unroll
  for (int t = 0; t < 8; t++) acc[t] = {0.f, 0.f, 0.f, 0.f};
#pragma unroll
  for (int j = 0; j < 4; j++) {
#pragma unroll
    for (int t = 0; t < 8; t++) {
      f16x8 bf = *(const f16x8*)&WT[(size_t)(t * 16 + l15) * 128 + kg * 8 + j * 32];
      acc[t] = __builtin_amdgcn_mfma_f32_16x16x32_f16(af[j], bf, acc[t], 0, 0, 0);
    }
  }

  int rbase = rowBlk + wv * 16 + kg * 4;
#pragma unroll
  for (int t = 0; t < 8; t++) {
    int ch = t * 16 + l15;
    float bb = bias[ch];
    float s = 0.f, q = 0.f;
#pragma unroll
    for (int r = 0; r < 4; r++) {
      int row = rbase + r;
      if (row < N) {
        float o = acc[t][r] + bb;
        __half oh = __float2half(o);
        Yh[(size_t)row * 128 + ch] = *(unsigned short*)&oh;
        s += o;
        q += o * o;
      }
    }
    s += __shfl_xor(s, 16); s += __shfl_xor(s, 32);
    q += __shfl_xor(q, 16); q += __shfl_xor(q, 32);
    if (kg == 0) { red[wv][0][ch] = s; red[wv][1][ch] = q; }
  }
  __syncthreads();
  int st = threadIdx.x >> 7, ch2 = threadIdx.x & 127;
  float v = red[0][st][ch2] + red[1][st][ch2] + red[2][st][ch2] + red[3][st][ch2];
  atomicAdd(&statCur[(blockIdx.x & 7) * 256 + st * 128 + ch2], v);
}

// ---- standalone W transpose (only layers l>=2) ----
__global__ __launch_bounds__(256) void k_wprep(const float* __restrict__ Wsrc,
                                               unsigned short* __restrict__ WT) {
  int i = blockIdx.x * 256 + threadIdx.x;
  int n = i & 127, k = i >> 7;
  ((__half*)WT)[(size_t)n * 128 + k] = __float2half(Wsrc[i]);
}

// ---- fused pool + MLP head: one block per graph, no atomics ----
__global__ __launch_bounds__(256) void k_poolmlp(
    const unsigned short* __restrict__ H16, const float* __restrict__ stat,
    const float* __restrict__ gamma, const float* __restrict__ beta, float invN,
    const int* __restrict__ gstart,
    const float* __restrict__ W1, const float* __restrict__ b1,
    const float* __restrict__ W2, const float* __restrict__ b2,
    float* __restrict__ out) {
  __shared__ float scsh[256];
  __shared__ float psum[256];
  __shared__ float P[128];
  __shared__ float z[64];
  if (threadIdx.x < 128) {
    int c = threadIdx.x;
    float ss = 0.f, qs = 0.f;
#pragma unroll
    for (int r = 0; r < 8; r++) {
      ss += stat[r * 256 + c];
      qs += stat[r * 256 + 128 + c];
    }
    float mu = ss * invN;
    float var = qs * invN - mu * mu;
    float sc = rsqrtf(var + 1e-5f) * gamma[c];
    scsh[c] = sc;
    scsh[128 + c] = beta[c] - mu * sc;
  }
  __syncthreads();

  int g = blockIdx.x;
  int beg = gstart[g], end = gstart[g + 1];
  int len = end - beg;
  int split = threadIdx.x >> 7, ch = threadIdx.x & 127;
  float sc = scsh[ch], sh = scsh[128 + ch];
  int r0 = beg + (len * split) / 2;
  int r1 = beg + (len * (split + 1)) / 2;
  float s = 0.f;
  for (int r = r0; r < r1; r++) {
    float v = __half2float(((const __half*)H16)[(size_t)r * 128 + ch]);
    s += fmaxf(fmaf(v, sc, sh), 0.f);
  }
  psum[threadIdx.x] = s;
  __syncthreads();
  if (threadIdx.x < 128)
    P[threadIdx.x] =
        (psum[threadIdx.x] + psum[threadIdx.x + 128]) / (float)(len > 1 ? len : 1);
  __syncthreads();
  if (threadIdx.x < 64) {
    int m = threadIdx.x;
    float a = b1[m];
    for (int k = 0; k < 128; k++) a = fmaf(P[k], W1[k * 64 + m], a);
    z[m] = fmaxf(a, 0.f);
  }
  __syncthreads();
  if (threadIdx.x == 0) {
    float a = b2[0];
    for (int m = 0; m < 64; m++) a = fmaf(z[m], W2[m], a);
    out[g] = 1.f / (1.f + expf(-a));
  }
}

// ---------------------------------------------------------------------------

extern "C" void kernel_launch(void* const* d_in, const int* in_sizes, int n_in,
                              void* d_out, int out_size, void* d_ws, size_t ws_size,
                              hipStream_t stream) {
  const float* x      = (const float*)d_in[0];
  const int*   ei     = (const int*)d_in[1];
  const int*   batch  = (const int*)d_in[2];
  const float* W_enc  = (const float*)d_in[3];
  const float* b_enc  = (const float*)d_in[4];
  const float* Wc     = (const float*)d_in[5];
  const float* bc     = (const float*)d_in[6];
  const float* gamma  = (const float*)d_in[7];
  const float* beta   = (const float*)d_in[8];
  const float* W1     = (const float*)d_in[9];
  const float* b1     = (const float*)d_in[10];
  const float* W2     = (const float*)d_in[11];
  const float* b2     = (const float*)d_in[12];
  float* out = (float*)d_out;

  const int N = in_sizes[2];         // 50000
  const int E = in_sizes[1] / 2;     // 500000
  const int NL = in_sizes[6] / 128;  // 2 layers

  size_t off = 0;
  auto alloc = [&](size_t bytes) {
    void* p = (char*)d_ws + off;
    off += (bytes + 255) & ~(size_t)255;
    return p;
  };
  unsigned short* h16a = (unsigned short*)alloc((size_t)N * 128 * 2);
  unsigned short* h16b = (unsigned short*)alloc((size_t)N * 128 * 2);
  int*   deg    = (int*)alloc((size_t)N * 4);
  float* dinv   = (float*)alloc((size_t)N * 4);
  int*   rowptr = (int*)alloc((size_t)(N + 1) * 4);
  int*   cursor = (int*)alloc((size_t)N * 4);
  int*   colx   = (int*)alloc((size_t)(E + N) * 4);
  int*   blksum = (int*)alloc(1024 * 4);
  float* bnstat = (float*)alloc((size_t)NL * 2048 * 4);  // NL x 8 reps x 256
  int*   gstart = (int*)alloc(65 * 4);
  unsigned short* MT  = (unsigned short*)alloc(128 * 64 * 2);
  unsigned short* WT1 = (unsigned short*)alloc(128 * 128 * 2);
  float* bfold  = (float*)alloc(128 * 4);
  unsigned* xs  = (unsigned*)alloc((size_t)N * 64 * 2);

  int nbN = (N + 255) / 256;
  int nbEN = (E + N + 255) / 256;
  float invN = 1.f / (float)N;
  int tiles = (N + 63) / 64;

  k_setup<<<nbN + 130, 256, 0, stream>>>(
      deg, bnstat, NL * 2048, N, nbN, W_enc, b_enc, Wc, MT, bfold, NL,
      Wc + (size_t)128 * 128, WT1, batch, gstart);
  k_deg<<<(E + 255) / 256, 256, 0, stream>>>(ei, E, deg);
  k_scan_a<<<nbN, 256, 0, stream>>>(deg, N, rowptr, blksum);
  k_scan_c<<<nbN, 256, 0, stream>>>(deg, N, E + N, blksum, rowptr, cursor, dinv);
  k_fillprep<<<nbEN + (N * 16 + 255) / 256, 256, 0, stream>>>(
      ei, E, N, nbEN, cursor, colx, x, dinv, xs);

  // ---- layer 0: fused agg + GEMM (encoder folded) ----
  k_aggemm0<<<tiles, 256, 0, stream>>>((const uint2*)xs, rowptr, colx, dinv,
                                       MT, bc, bfold, bnstat, h16a, N);

  // ---- layers 1..NL-1: fused BN+ReLU-gather + agg + GEMM ----
  unsigned short* cur = h16a;
  unsigned short* nxt = h16b;
  for (int l = 1; l < NL; l++) {
    if (l > 1)   // WT1 for l==1 comes from k_setup
      k_wprep<<<64, 256, 0, stream>>>(Wc + (size_t)l * 128 * 128, WT1);
    k_aggemm1<<<tiles, 256, 0, stream>>>(
        cur, rowptr, colx, dinv, WT1, bnstat + (l - 1) * 2048,
        gamma + (l - 1) * 128, beta + (l - 1) * 128, invN, bc + l * 128,
        bnstat + l * 2048, nxt, N);
    unsigned short* tmp = cur; cur = nxt; nxt = tmp;
  }

  k_poolmlp<<<64, 256, 0, stream>>>(cur, bnstat + (NL - 1) * 2048,
                                    gamma + (NL - 1) * 128,
                                    beta + (NL - 1) * 128, invN, gstart,
                                    W1, b1, W2, b2, out);
}

// Round 13
// 282.699 us; speedup vs baseline: 1.2708x; 1.2708x over previous
//
#include <hip/hip_runtime.h>
#include <hip/hip_bf16.h>
#include <hip/hip_fp16.h>
#include <math.h>

// ---------------------------------------------------------------------------
// GCN forward on MI355X. fp16 gather tables + fp16 MFMA GEMMs (fp32 accum).
// Structure (R5): aggregate FIRST (linear), GEMM after.
//   k_aggemm0 = agg0+gemm0 (agg to LDS, MFMA from LDS, W via L1)
//   k_aggemm1 = prep1+agg1+gemm1 (BN+ReLU+dinv applied inline at gather)
//   k_pool (512 blk, half2 loads) -> k_mlp   [R10: poolmlp fusion REVERTED]
// Lessons: R2 unroll-spill; R5 gather=past-L2-BW-bound; R6 MFMA;
//   R7 W-stage-once + A-direct; R8 fuse small kernels, inline bnfinal;
//   R9 scan_b folded, aggemm fusions (+20us);
//   R10 pool+mlp fusion cut pooling to 64 blocks -> 121us latency-bound
//       (occ 2.4%, 54 GB/s scalar fp16 loads). Parallelism > dispatch-gap.
//   R11/R12: no data (GPU acquisition timeouts) -> resubmitted unchanged.
// ---------------------------------------------------------------------------

typedef _Float16 f16x8 __attribute__((ext_vector_type(8)));
typedef float f32x4 __attribute__((ext_vector_type(4)));

__device__ inline unsigned pack2(float a, float b) {
  union { __half2 h; unsigned u; } p;
  p.h = __floats2half2_rn(a, b);
  return p.u;
}
__device__ inline float2 unpack2(unsigned u) {
  union { unsigned u; __half2 h; } p;
  p.u = u;
  return __half22float2(p.h);
}

// ---- setup: deg=1 / bnstat=0 / pooled=0 + encoder fold + W1 transpose + gstart
__global__ __launch_bounds__(256) void k_setup(
    int* __restrict__ deg, float* __restrict__ bnstat, int statTotal,
    float* __restrict__ pooled, int N, int nbN,
    const float* __restrict__ W_enc, const float* __restrict__ b_enc,
    const float* __restrict__ Wc, unsigned short* __restrict__ MT,
    float* __restrict__ bfold, int NL,
    const float* __restrict__ Wc1, unsigned short* __restrict__ WT1,
    const int* __restrict__ batch, int* __restrict__ gstart) {
  int b = blockIdx.x;
  if (b < nbN) {                       // init
    int i = b * 256 + threadIdx.x;
    if (i < N) deg[i] = 1;             // self-loop
    if (i < statTotal) bnstat[i] = 0.f;
    if (i < 64 * 128) pooled[i] = 0.f;
    return;
  }
  b -= nbN;
  if (b < 65) {                        // fold: MT[n][k] fp16, bfold
    if (threadIdx.x < 128) {
      int n = threadIdx.x;
      int k = b;
      const float* arow = (k < 64) ? (W_enc + (size_t)k * 128) : b_enc;
      float acc = 0.f;
      for (int j = 0; j < 128; j++)
        acc = fmaf(arow[j], Wc[(size_t)j * 128 + n], acc);
      if (k < 64) ((__half*)MT)[(size_t)n * 64 + k] = __float2half(acc);
      else bfold[n] = acc;
    }
    return;
  }
  b -= 65;
  if (b < 64) {                        // wprep for layer 1
    if (NL > 1) {
      int i = b * 256 + threadIdx.x;   // 16384
      int n = i & 127, k = i >> 7;
      ((__half*)WT1)[(size_t)n * 128 + k] = __float2half(Wc1[i]);
    }
    return;
  }
  int g = threadIdx.x;                 // gstart (last block)
  if (g <= 64) {
    int lo = 0, hi = N;
    while (lo < hi) {
      int mid = (lo + hi) >> 1;
      if (batch[mid] < g) lo = mid + 1;
      else hi = mid;
    }
    gstart[g] = lo;
  }
}

__global__ __launch_bounds__(256) void k_deg(const int* __restrict__ ei, int E,
                                             int* __restrict__ deg) {
  int i = blockIdx.x * 256 + threadIdx.x;
  if (i < E) atomicAdd(&deg[ei[E + i]], 1);   // dst row
}

// ---- scan: block-local exclusive + raw block totals ----
__global__ __launch_bounds__(256) void k_scan_a(const int* __restrict__ deg, int N,
                                                int* __restrict__ rowptr,
                                                int* __restrict__ blksum) {
  __shared__ int s[256];
  int t = threadIdx.x;
  int i = blockIdx.x * 256 + t;
  int v = (i < N) ? deg[i] : 0;
  s[t] = v;
  __syncthreads();
  for (int off = 1; off < 256; off <<= 1) {
    int x = (t >= off) ? s[t - off] : 0;
    __syncthreads();
    s[t] += x;
    __syncthreads();
  }
  if (i < N) rowptr[i] = s[t] - v;            // exclusive (partial)
  if (t == 255) blksum[blockIdx.x] = s[255];  // raw block total
}

// ---- scan_c: per-block prefix over blksum (scan_b fused, R9) ----
__global__ __launch_bounds__(256) void k_scan_c(const int* __restrict__ deg, int N,
                                                int total,
                                                const int* __restrict__ blksum,
                                                int* __restrict__ rowptr,
                                                int* __restrict__ cursor,
                                                float* __restrict__ dinv) {
  __shared__ int red[256];
  int t = threadIdx.x, b = blockIdx.x;
  int acc = 0;
  for (int j = t; j < b; j += 256) acc += blksum[j];
  red[t] = acc;
  __syncthreads();
  for (int off = 128; off > 0; off >>= 1) {
    if (t < off) red[t] += red[t + off];
    __syncthreads();
  }
  int prefix = red[0];
  int i = b * 256 + t;
  if (i < N) {
    int rp = rowptr[i] + prefix;
    rowptr[i] = rp;
    cursor[i] = rp;
    dinv[i] = rsqrtf((float)deg[i]);
  } else if (i == N) {
    rowptr[N] = total;
  }
}

// ---- CSR fill + prep0 (xs fp16 = x*dinv) in one dispatch ----
__global__ __launch_bounds__(256) void k_fillprep(
    const int* __restrict__ ei, int E, int N, int nbEN,
    int* __restrict__ cursor, int* __restrict__ colx,
    const float* __restrict__ x, const float* __restrict__ dinv,
    unsigned* __restrict__ xs2) {
  int b = blockIdx.x;
  if (b < nbEN) {
    int i = b * 256 + threadIdx.x;
    if (i < E) {
      int s = ei[i];
      int d = ei[E + i];
      int pos = atomicAdd(&cursor[d], 1);
      colx[pos] = s;
    } else if (i < E + N) {
      int j = i - E;
      int pos = atomicAdd(&cursor[j], 1);
      colx[pos] = j;                   // self-loop entry
    }
    return;
  }
  b -= nbEN;
  int i = b * 256 + threadIdx.x;
  if (i < N * 16) {
    int row = i >> 4;
    float4 v = ((const float4*)x)[i];
    float d = dinv[row];
    uint2 o;
    o.x = pack2(v.x * d, v.y * d);
    o.y = pack2(v.z * d, v.w * d);
    ((uint2*)xs2)[i] = o;
  }
}

// ---- fused agg0 + gemm0: block owns 64 rows ----
__global__ __launch_bounds__(256, 2) void k_aggemm0(
    const uint2* __restrict__ xs, const int* __restrict__ rowptr,
    const int* __restrict__ colx, const float* __restrict__ dinv,
    const unsigned short* __restrict__ MT,   // 128 x 64 fp16 (n-major)
    const float* __restrict__ bias,          // bc0
    const float* __restrict__ bias2,         // bfold
    float* __restrict__ stat,                // 8 x 256 replicas
    unsigned short* __restrict__ Yh, int N) {
  constexpr int KP = 68;                     // +4 fp16 pad -> 2-way banks
  __shared__ unsigned short Al[64 * KP];
  __shared__ float wvl[64];
  __shared__ float red[4][2][128];

  int lane = threadIdx.x & 63;
  int wv = threadIdx.x >> 6;
  int grp = lane >> 4, l16 = lane & 15;
  int rowBlk = blockIdx.x * 64;

#pragma unroll 1
  for (int it = 0; it < 4; it++) {
    int lr = it * 16 + wv * 4 + grp;
    int i = rowBlk + lr;
    float s0 = 0.f, s1 = 0.f, s2 = 0.f, s3 = 0.f, sd = 0.f;
    if (i < N) {
      int beg = rowptr[i], end = rowptr[i + 1];
      int e = beg;
#pragma unroll 1
      for (; e + 8 <= end; e += 8) {
        int ix[8];
#pragma unroll
        for (int u = 0; u < 8; u++) ix[u] = colx[e + u];
        uint2 v[8];
        float dd[8];
#pragma unroll
        for (int u = 0; u < 8; u++) { v[u] = xs[(size_t)ix[u] * 16 + l16]; dd[u] = dinv[ix[u]]; }
#pragma unroll
        for (int u = 0; u < 8; u++) {
          float2 a = unpack2(v[u].x), b = unpack2(v[u].y);
          s0 += a.x; s1 += a.y; s2 += b.x; s3 += b.y;
          sd += dd[u];
        }
      }
#pragma unroll 1
      for (; e < end; e++) {
        int sr = colx[e];
        uint2 vv = xs[(size_t)sr * 16 + l16];
        float2 a = unpack2(vv.x), b = unpack2(vv.y);
        s0 += a.x; s1 += a.y; s2 += b.x; s3 += b.y;
        sd += dinv[sr];
      }
    }
    float di = (i < N) ? dinv[i] : 0.f;
    *(uint2*)&Al[lr * KP + l16 * 4] =
        make_uint2(pack2(s0 * di, s1 * di), pack2(s2 * di, s3 * di));
    if (l16 == 0) wvl[lr] = di * sd;
  }
  __syncthreads();

  int l15 = lane & 15;
  int kg = lane >> 4;
  f16x8 af[2];
#pragma unroll
  for (int j = 0; j < 2; j++)
    af[j] = *(const f16x8*)&Al[(wv * 16 + l15) * KP + kg * 8 + j * 32];

  f32x4 acc[8];
#pragma unroll
  for (int t = 0; t < 8; t++) acc[t] = {0.f, 0.f, 0.f, 0.f};
#pragma unroll
  for (int j = 0; j < 2; j++) {
#pragma unroll
    for (int t = 0; t < 8; t++) {
      f16x8 bf = *(const f16x8*)&MT[(size_t)(t * 16 + l15) * 64 + kg * 8 + j * 32];
      acc[t] = __builtin_amdgcn_mfma_f32_16x16x32_f16(af[j], bf, acc[t], 0, 0, 0);
    }
  }

  int rbaseL = wv * 16 + kg * 4;
  int rbase = rowBlk + rbaseL;
  float wrow[4];
#pragma unroll
  for (int r = 0; r < 4; r++) wrow[r] = wvl[rbaseL + r];

#pragma unroll
  for (int t = 0; t < 8; t++) {
    int ch = t * 16 + l15;
    float bb = bias[ch];
    float b2v = bias2[ch];
    float s = 0.f, q = 0.f;
#pragma unroll
    for (int r = 0; r < 4; r++) {
      int row = rbase + r;
      if (row < N) {
        float o = fmaf(wrow[r], b2v, acc[t][r] + bb);
        __half oh = __float2half(o);
        Yh[(size_t)row * 128 + ch] = *(unsigned short*)&oh;
        s += o;
        q += o * o;
      }
    }
    s += __shfl_xor(s, 16); s += __shfl_xor(s, 32);
    q += __shfl_xor(q, 16); q += __shfl_xor(q, 32);
    if (kg == 0) { red[wv][0][ch] = s; red[wv][1][ch] = q; }
  }
  __syncthreads();
  int st = threadIdx.x >> 7, ch2 = threadIdx.x & 127;
  float v = red[0][st][ch2] + red[1][st][ch2] + red[2][st][ch2] + red[3][st][ch2];
  atomicAdd(&stat[(blockIdx.x & 7) * 256 + st * 128 + ch2], v);
}

// ---- fused prep1 + agg1 + gemm1: BN+ReLU+dinv applied inline at gather ----
__global__ __launch_bounds__(256, 2) void k_aggemm1(
    const unsigned short* __restrict__ Hprev,  // N x 128 fp16
    const int* __restrict__ rowptr, const int* __restrict__ colx,
    const float* __restrict__ dinv,
    const unsigned short* __restrict__ WT,     // 128 x 128 fp16 (n-major)
    const float* __restrict__ statPrev, const float* __restrict__ gamma,
    const float* __restrict__ beta, float invN,
    const float* __restrict__ bias,            // bc[l]
    float* __restrict__ statCur, unsigned short* __restrict__ Yh, int N) {
  constexpr int KP = 136;                      // +8 fp16 pad -> 2-way banks
  __shared__ unsigned short Al[64 * KP];
  __shared__ float scsh[256];
  __shared__ float red[4][2][128];

  if (threadIdx.x < 128) {
    int c = threadIdx.x;
    float ss = 0.f, qs = 0.f;
#pragma unroll
    for (int r = 0; r < 8; r++) {
      ss += statPrev[r * 256 + c];
      qs += statPrev[r * 256 + 128 + c];
    }
    float mu = ss * invN;
    float var = qs * invN - mu * mu;
    float sc = rsqrtf(var + 1e-5f) * gamma[c];
    scsh[c] = sc;
    scsh[128 + c] = beta[c] - mu * sc;
  }
  __syncthreads();

  int lane = threadIdx.x & 63;
  int wv = threadIdx.x >> 6;
  int half = lane >> 5, l32 = lane & 31;
  int rowBlk = blockIdx.x * 64;
  const uint2* Hp = (const uint2*)Hprev;
  float4 sc = ((const float4*)scsh)[l32];
  float4 sh = ((const float4*)(scsh + 128))[l32];

#pragma unroll 1
  for (int it = 0; it < 8; it++) {
    int lr = it * 8 + wv * 2 + half;
    int i = rowBlk + lr;
    float4 s = make_float4(0.f, 0.f, 0.f, 0.f);
    if (i < N) {
      int beg = rowptr[i], end = rowptr[i + 1];
      int e = beg;
#pragma unroll 1
      for (; e + 4 <= end; e += 4) {
        int i0 = colx[e + 0], i1 = colx[e + 1], i2 = colx[e + 2], i3 = colx[e + 3];
        uint2 v0 = Hp[(size_t)i0 * 32 + l32];
        uint2 v1 = Hp[(size_t)i1 * 32 + l32];
        uint2 v2 = Hp[(size_t)i2 * 32 + l32];
        uint2 v3 = Hp[(size_t)i3 * 32 + l32];
        float d0 = dinv[i0], d1 = dinv[i1], d2 = dinv[i2], d3 = dinv[i3];
        float2 a, b;
        a = unpack2(v0.x); b = unpack2(v0.y);
        s.x += fmaxf(fmaf(a.x, sc.x, sh.x), 0.f) * d0;
        s.y += fmaxf(fmaf(a.y, sc.y, sh.y), 0.f) * d0;
        s.z += fmaxf(fmaf(b.x, sc.z, sh.z), 0.f) * d0;
        s.w += fmaxf(fmaf(b.y, sc.w, sh.w), 0.f) * d0;
        a = unpack2(v1.x); b = unpack2(v1.y);
        s.x += fmaxf(fmaf(a.x, sc.x, sh.x), 0.f) * d1;
        s.y += fmaxf(fmaf(a.y, sc.y, sh.y), 0.f) * d1;
        s.z += fmaxf(fmaf(b.x, sc.z, sh.z), 0.f) * d1;
        s.w += fmaxf(fmaf(b.y, sc.w, sh.w), 0.f) * d1;
        a = unpack2(v2.x); b = unpack2(v2.y);
        s.x += fmaxf(fmaf(a.x, sc.x, sh.x), 0.f) * d2;
        s.y += fmaxf(fmaf(a.y, sc.y, sh.y), 0.f) * d2;
        s.z += fmaxf(fmaf(b.x, sc.z, sh.z), 0.f) * d2;
        s.w += fmaxf(fmaf(b.y, sc.w, sh.w), 0.f) * d2;
        a = unpack2(v3.x); b = unpack2(v3.y);
        s.x += fmaxf(fmaf(a.x, sc.x, sh.x), 0.f) * d3;
        s.y += fmaxf(fmaf(a.y, sc.y, sh.y), 0.f) * d3;
        s.z += fmaxf(fmaf(b.x, sc.z, sh.z), 0.f) * d3;
        s.w += fmaxf(fmaf(b.y, sc.w, sh.w), 0.f) * d3;
      }
#pragma unroll 1
      for (; e < end; e++) {
        int sr = colx[e];
        uint2 vv = Hp[(size_t)sr * 32 + l32];
        float dsr = dinv[sr];
        float2 a = unpack2(vv.x), b = unpack2(vv.y);
        s.x += fmaxf(fmaf(a.x, sc.x, sh.x), 0.f) * dsr;
        s.y += fmaxf(fmaf(a.y, sc.y, sh.y), 0.f) * dsr;
        s.z += fmaxf(fmaf(b.x, sc.z, sh.z), 0.f) * dsr;
        s.w += fmaxf(fmaf(b.y, sc.w, sh.w), 0.f) * dsr;
      }
    }
    float di = (i < N) ? dinv[i] : 0.f;
    *(uint2*)&Al[lr * KP + l32 * 4] =
        make_uint2(pack2(s.x * di, s.y * di), pack2(s.z * di, s.w * di));
  }
  __syncthreads();

  int l15 = lane & 15;
  int kg = lane >> 4;
  f16x8 af[4];
#pragma unroll
  for (int j = 0; j < 4; j++)
    af[j] = *(const f16x8*)&Al[(wv * 16 + l15) * KP + kg * 8 + j * 32];

  f32x4 acc[8];
#pragma unroll
  for (int t = 0; t < 8; t++) acc[t] = {0.f, 0.f, 0.f, 0.f};
#pragma unroll
  for (int j = 0; j < 4; j++) {
#pragma unroll
    for (int t = 0; t < 8; t++) {
      f16x8 bf = *(const f16x8*)&WT[(size_t)(t * 16 + l15) * 128 + kg * 8 + j * 32];
      acc[t] = __builtin_amdgcn_mfma_f32_16x16x32_f16(af[j], bf, acc[t], 0, 0, 0);
    }
  }

  int rbase = rowBlk + wv * 16 + kg * 4;
#pragma unroll
  for (int t = 0; t < 8; t++) {
    int ch = t * 16 + l15;
    float bb = bias[ch];
    float s = 0.f, q = 0.f;
#pragma unroll
    for (int r = 0; r < 4; r++) {
      int row = rbase + r;
      if (row < N) {
        float o = acc[t][r] + bb;
        __half oh = __float2half(o);
        Yh[(size_t)row * 128 + ch] = *(unsigned short*)&oh;
        s += o;
        q += o * o;
      }
    }
    s += __shfl_xor(s, 16); s += __shfl_xor(s, 32);
    q += __shfl_xor(q, 16); q += __shfl_xor(q, 32);
    if (kg == 0) { red[wv][0][ch] = s; red[wv][1][ch] = q; }
  }
  __syncthreads();
  int st = threadIdx.x >> 7, ch2 = threadIdx.x & 127;
  float v = red[0][st][ch2] + red[1][st][ch2] + red[2][st][ch2] + red[3][st][ch2];
  atomicAdd(&statCur[(blockIdx.x & 7) * 256 + st * 128 + ch2], v);
}

// ---- standalone W transpose (only layers l>=2) ----
__global__ __launch_bounds__(256) void k_wprep(const float* __restrict__ Wsrc,
                                               unsigned short* __restrict__ WT) {
  int i = blockIdx.x * 256 + threadIdx.x;
  int n = i & 127, k = i >> 7;
  ((__half*)WT)[(size_t)n * 128 + k] = __float2half(Wsrc[i]);
}

// ---- Pool: BN inline + ReLU + segment sum. 512 blocks, half2 loads (R10) ----
__global__ __launch_bounds__(256) void k_pool(
    const unsigned* __restrict__ H16u,       // N x 64 half2-pairs
    const float* __restrict__ stat, const float* __restrict__ gamma,
    const float* __restrict__ beta, float invN,
    const int* __restrict__ gstart, float* __restrict__ pooled) {
  __shared__ float scsh[256];
  __shared__ float red[4][128];
  if (threadIdx.x < 128) {
    int c = threadIdx.x;
    float ss = 0.f, qs = 0.f;
#pragma unroll
    for (int r = 0; r < 8; r++) {
      ss += stat[r * 256 + c];
      qs += stat[r * 256 + 128 + c];
    }
    float mu = ss * invN;
    float var = qs * invN - mu * mu;
    float sc = rsqrtf(var + 1e-5f) * gamma[c];
    scsh[c] = sc;
    scsh[128 + c] = beta[c] - mu * sc;
  }
  __syncthreads();

  int g = blockIdx.x >> 3;
  int part = blockIdx.x & 7;
  int beg = gstart[g], end = gstart[g + 1];
  int len = end - beg;
  int p0 = beg + (len * part) / 8;
  int p1 = beg + (len * (part + 1)) / 8;

  int l64 = threadIdx.x & 63;      // channel pair
  int rs = threadIdx.x >> 6;       // 0..3 row substream
  int c0 = l64 * 2;
  float sc0 = scsh[c0], sc1 = scsh[c0 + 1];
  float sh0 = scsh[128 + c0], sh1 = scsh[128 + c0 + 1];
  int plen = p1 - p0;
  int q0 = p0 + (plen * rs) / 4;
  int q1 = p0 + (plen * (rs + 1)) / 4;

  float a0 = 0.f, a1 = 0.f;
  for (int r = q0; r < q1; r++) {
    float2 f = unpack2(H16u[(size_t)r * 64 + l64]);
    a0 += fmaxf(fmaf(f.x, sc0, sh0), 0.f);
    a1 += fmaxf(fmaf(f.y, sc1, sh1), 0.f);
  }
  red[rs][c0] = a0;
  red[rs][c0 + 1] = a1;
  __syncthreads();
  if (threadIdx.x < 128) {
    float s = red[0][threadIdx.x] + red[1][threadIdx.x] +
              red[2][threadIdx.x] + red[3][threadIdx.x];
    atomicAdd(&pooled[g * 128 + threadIdx.x], s);
  }
}

// ---- Head MLP (1 block) ----
__global__ __launch_bounds__(256) void k_mlp(const float* __restrict__ pooled,
                                             const int* __restrict__ gstart,
                                             const float* __restrict__ W1,
                                             const float* __restrict__ b1,
                                             const float* __restrict__ W2,
                                             const float* __restrict__ b2,
                                             float* __restrict__ out) {
  __shared__ float P[64 * 128];
  __shared__ float Z[64 * 64];
  for (int i = threadIdx.x; i < 64 * 128; i += 256) {
    int g = i >> 7;
    int cnt = gstart[g + 1] - gstart[g];
    P[i] = pooled[i] / (float)(cnt > 1 ? cnt : 1);
  }
  __syncthreads();
  for (int i = threadIdx.x; i < 64 * 64; i += 256) {
    int g = i >> 6, m = i & 63;
    float acc = b1[m];
    for (int k = 0; k < 128; k++) acc += P[(g << 7) + k] * W1[k * 64 + m];
    Z[i] = fmaxf(acc, 0.f);
  }
  __syncthreads();
  if (threadIdx.x < 64) {
    int g = threadIdx.x;
    float acc = b2[0];
    for (int m = 0; m < 64; m++) acc += Z[(g << 6) + m] * W2[m];
    out[g] = 1.f / (1.f + expf(-acc));
  }
}

// ---------------------------------------------------------------------------

extern "C" void kernel_launch(void* const* d_in, const int* in_sizes, int n_in,
                              void* d_out, int out_size, void* d_ws, size_t ws_size,
                              hipStream_t stream) {
  const float* x      = (const float*)d_in[0];
  const int*   ei     = (const int*)d_in[1];
  const int*   batch  = (const int*)d_in[2];
  const float* W_enc  = (const float*)d_in[3];
  const float* b_enc  = (const float*)d_in[4];
  const float* Wc     = (const float*)d_in[5];
  const float* bc     = (const float*)d_in[6];
  const float* gamma  = (const float*)d_in[7];
  const float* beta   = (const float*)d_in[8];
  const float* W1     = (const float*)d_in[9];
  const float* b1     = (const float*)d_in[10];
  const float* W2     = (const float*)d_in[11];
  const float* b2     = (const float*)d_in[12];
  float* out = (float*)d_out;

  const int N = in_sizes[2];         // 50000
  const int E = in_sizes[1] / 2;     // 500000
  const int NL = in_sizes[6] / 128;  // 2 layers

  size_t off = 0;
  auto alloc = [&](size_t bytes) {
    void* p = (char*)d_ws + off;
    off += (bytes + 255) & ~(size_t)255;
    return p;
  };
  unsigned short* h16a = (unsigned short*)alloc((size_t)N * 128 * 2);
  unsigned short* h16b = (unsigned short*)alloc((size_t)N * 128 * 2);
  int*   deg    = (int*)alloc((size_t)N * 4);
  float* dinv   = (float*)alloc((size_t)N * 4);
  int*   rowptr = (int*)alloc((size_t)(N + 1) * 4);
  int*   cursor = (int*)alloc((size_t)N * 4);
  int*   colx   = (int*)alloc((size_t)(E + N) * 4);
  int*   blksum = (int*)alloc(1024 * 4);
  float* bnstat = (float*)alloc((size_t)NL * 2048 * 4);  // NL x 8 reps x 256
  float* pooled = (float*)alloc(64 * 128 * 4);
  int*   gstart = (int*)alloc(65 * 4);
  unsigned short* MT  = (unsigned short*)alloc(128 * 64 * 2);
  unsigned short* WT1 = (unsigned short*)alloc(128 * 128 * 2);
  float* bfold  = (float*)alloc(128 * 4);
  unsigned* xs  = (unsigned*)alloc((size_t)N * 64 * 2);

  int nbN = (N + 255) / 256;
  int nbEN = (E + N + 255) / 256;
  float invN = 1.f / (float)N;
  int tiles = (N + 63) / 64;

  k_setup<<<nbN + 130, 256, 0, stream>>>(
      deg, bnstat, NL * 2048, pooled, N, nbN, W_enc, b_enc, Wc, MT, bfold, NL,
      Wc + (size_t)128 * 128, WT1, batch, gstart);
  k_deg<<<(E + 255) / 256, 256, 0, stream>>>(ei, E, deg);
  k_scan_a<<<nbN, 256, 0, stream>>>(deg, N, rowptr, blksum);
  k_scan_c<<<nbN, 256, 0, stream>>>(deg, N, E + N, blksum, rowptr, cursor, dinv);
  k_fillprep<<<nbEN + (N * 16 + 255) / 256, 256, 0, stream>>>(
      ei, E, N, nbEN, cursor, colx, x, dinv, xs);

  // ---- layer 0: fused agg + GEMM (encoder folded) ----
  k_aggemm0<<<tiles, 256, 0, stream>>>((const uint2*)xs, rowptr, colx, dinv,
                                       MT, bc, bfold, bnstat, h16a, N);

  // ---- layers 1..NL-1: fused BN+ReLU-gather + agg + GEMM ----
  unsigned short* cur = h16a;
  unsigned short* nxt = h16b;
  for (int l = 1; l < NL; l++) {
    if (l > 1)   // WT1 for l==1 comes from k_setup
      k_wprep<<<64, 256, 0, stream>>>(Wc + (size_t)l * 128 * 128, WT1);
    k_aggemm1<<<tiles, 256, 0, stream>>>(
        cur, rowptr, colx, dinv, WT1, bnstat + (l - 1) * 2048,
        gamma + (l - 1) * 128, beta + (l - 1) * 128, invN, bc + l * 128,
        bnstat + l * 2048, nxt, N);
    unsigned short* tmp = cur; cur = nxt; nxt = tmp;
  }

  k_pool<<<64 * 8, 256, 0, stream>>>((const unsigned*)cur,
                                     bnstat + (NL - 1) * 2048,
                                     gamma + (NL - 1) * 128,
                                     beta + (NL - 1) * 128, invN, gstart,
                                     pooled);
  k_mlp<<<1, 256, 0, stream>>>(pooled, gstart, W1, b1, W2, b2, out);
}

// Round 14
// 258.522 us; speedup vs baseline: 1.3896x; 1.0935x over previous
//
#include <hip/hip_runtime.h>
#include <hip/hip_bf16.h>
#include <hip/hip_fp16.h>
#include <math.h>

// ---------------------------------------------------------------------------
// GCN forward on MI355X. fp16 gather tables + fp16 MFMA GEMMs (fp32 accum).
// Structure (R5): aggregate FIRST (linear), GEMM after.
//   k_aggemm0 = agg0+gemm0 ; k_aggemm1 = prep1+agg1+gemm1 (BN+ReLU inline)
//   k_pool (512 blk, half2) -> k_mlp
// Lessons: R2 unroll-spill; R5 gather=past-L2-BW/latency-bound; R6 MFMA;
//   R7 W-stage-once; R8 fuse small kernels; R9 aggemm fusions;
//   R10 pooling needs blocks (parallelism > dispatch-gap);
//   R13: fused grid=782 blocks grid-limited the gather (occ 27%, 62.7us)
//        -> 32-row tiles (grid 1563, ~6 blk/CU) + 8-deep gather unroll.
// ---------------------------------------------------------------------------

typedef _Float16 f16x8 __attribute__((ext_vector_type(8)));
typedef float f32x4 __attribute__((ext_vector_type(4)));

__device__ inline unsigned pack2(float a, float b) {
  union { __half2 h; unsigned u; } p;
  p.h = __floats2half2_rn(a, b);
  return p.u;
}
__device__ inline float2 unpack2(unsigned u) {
  union { unsigned u; __half2 h; } p;
  p.u = u;
  return __half22float2(p.h);
}

// ---- setup: deg=1 / bnstat=0 / pooled=0 + encoder fold + W1 transpose + gstart
__global__ __launch_bounds__(256) void k_setup(
    int* __restrict__ deg, float* __restrict__ bnstat, int statTotal,
    float* __restrict__ pooled, int N, int nbN,
    const float* __restrict__ W_enc, const float* __restrict__ b_enc,
    const float* __restrict__ Wc, unsigned short* __restrict__ MT,
    float* __restrict__ bfold, int NL,
    const float* __restrict__ Wc1, unsigned short* __restrict__ WT1,
    const int* __restrict__ batch, int* __restrict__ gstart) {
  int b = blockIdx.x;
  if (b < nbN) {                       // init
    int i = b * 256 + threadIdx.x;
    if (i < N) deg[i] = 1;             // self-loop
    if (i < statTotal) bnstat[i] = 0.f;
    if (i < 64 * 128) pooled[i] = 0.f;
    return;
  }
  b -= nbN;
  if (b < 65) {                        // fold: MT[n][k] fp16, bfold
    if (threadIdx.x < 128) {
      int n = threadIdx.x;
      int k = b;
      const float* arow = (k < 64) ? (W_enc + (size_t)k * 128) : b_enc;
      float acc = 0.f;
      for (int j = 0; j < 128; j++)
        acc = fmaf(arow[j], Wc[(size_t)j * 128 + n], acc);
      if (k < 64) ((__half*)MT)[(size_t)n * 64 + k] = __float2half(acc);
      else bfold[n] = acc;
    }
    return;
  }
  b -= 65;
  if (b < 64) {                        // wprep for layer 1
    if (NL > 1) {
      int i = b * 256 + threadIdx.x;   // 16384
      int n = i & 127, k = i >> 7;
      ((__half*)WT1)[(size_t)n * 128 + k] = __float2half(Wc1[i]);
    }
    return;
  }
  int g = threadIdx.x;                 // gstart (last block)
  if (g <= 64) {
    int lo = 0, hi = N;
    while (lo < hi) {
      int mid = (lo + hi) >> 1;
      if (batch[mid] < g) lo = mid + 1;
      else hi = mid;
    }
    gstart[g] = lo;
  }
}

__global__ __launch_bounds__(256) void k_deg(const int* __restrict__ ei, int E,
                                             int* __restrict__ deg) {
  int i = blockIdx.x * 256 + threadIdx.x;
  if (i < E) atomicAdd(&deg[ei[E + i]], 1);   // dst row
}

// ---- scan: block-local exclusive + raw block totals ----
__global__ __launch_bounds__(256) void k_scan_a(const int* __restrict__ deg, int N,
                                                int* __restrict__ rowptr,
                                                int* __restrict__ blksum) {
  __shared__ int s[256];
  int t = threadIdx.x;
  int i = blockIdx.x * 256 + t;
  int v = (i < N) ? deg[i] : 0;
  s[t] = v;
  __syncthreads();
  for (int off = 1; off < 256; off <<= 1) {
    int x = (t >= off) ? s[t - off] : 0;
    __syncthreads();
    s[t] += x;
    __syncthreads();
  }
  if (i < N) rowptr[i] = s[t] - v;            // exclusive (partial)
  if (t == 255) blksum[blockIdx.x] = s[255];  // raw block total
}

// ---- scan_c: per-block prefix over blksum (scan_b fused, R9) ----
__global__ __launch_bounds__(256) void k_scan_c(const int* __restrict__ deg, int N,
                                                int total,
                                                const int* __restrict__ blksum,
                                                int* __restrict__ rowptr,
                                                int* __restrict__ cursor,
                                                float* __restrict__ dinv) {
  __shared__ int red[256];
  int t = threadIdx.x, b = blockIdx.x;
  int acc = 0;
  for (int j = t; j < b; j += 256) acc += blksum[j];
  red[t] = acc;
  __syncthreads();
  for (int off = 128; off > 0; off >>= 1) {
    if (t < off) red[t] += red[t + off];
    __syncthreads();
  }
  int prefix = red[0];
  int i = b * 256 + t;
  if (i < N) {
    int rp = rowptr[i] + prefix;
    rowptr[i] = rp;
    cursor[i] = rp;
    dinv[i] = rsqrtf((float)deg[i]);
  } else if (i == N) {
    rowptr[N] = total;
  }
}

// ---- CSR fill + prep0 (xs fp16 = x*dinv) in one dispatch ----
__global__ __launch_bounds__(256) void k_fillprep(
    const int* __restrict__ ei, int E, int N, int nbEN,
    int* __restrict__ cursor, int* __restrict__ colx,
    const float* __restrict__ x, const float* __restrict__ dinv,
    unsigned* __restrict__ xs2) {
  int b = blockIdx.x;
  if (b < nbEN) {
    int i = b * 256 + threadIdx.x;
    if (i < E) {
      int s = ei[i];
      int d = ei[E + i];
      int pos = atomicAdd(&cursor[d], 1);
      colx[pos] = s;
    } else if (i < E + N) {
      int j = i - E;
      int pos = atomicAdd(&cursor[j], 1);
      colx[pos] = j;                   // self-loop entry
    }
    return;
  }
  b -= nbEN;
  int i = b * 256 + threadIdx.x;
  if (i < N * 16) {
    int row = i >> 4;
    float4 v = ((const float4*)x)[i];
    float d = dinv[row];
    uint2 o;
    o.x = pack2(v.x * d, v.y * d);
    o.y = pack2(v.z * d, v.w * d);
    ((uint2*)xs2)[i] = o;
  }
}

// ---- fused agg0 + gemm0: block owns 32 rows (R13) ----
// Gather: quarter-wave/row (16 rows/iter x 2 iters), 8-deep unroll.
// MFMA: wave (wr=wv&1, wc=wv>>1) -> 16 rows x 64 cols, K=64.
__global__ __launch_bounds__(256, 4) void k_aggemm0(
    const uint2* __restrict__ xs, const int* __restrict__ rowptr,
    const int* __restrict__ colx, const float* __restrict__ dinv,
    const unsigned short* __restrict__ MT,   // 128 x 64 fp16 (n-major)
    const float* __restrict__ bias,          // bc0
    const float* __restrict__ bias2,         // bfold
    float* __restrict__ stat,                // 8 x 256 replicas
    unsigned short* __restrict__ Yh, int N) {
  constexpr int KP = 68;                     // +4 fp16 pad
  __shared__ unsigned short Al[32 * KP];
  __shared__ float wvl[32];
  __shared__ float red[2][2][128];

  int lane = threadIdx.x & 63;
  int wv = threadIdx.x >> 6;
  int grp = lane >> 4, l16 = lane & 15;
  int rowBlk = blockIdx.x * 32;

#pragma unroll 1
  for (int it = 0; it < 2; it++) {
    int lr = it * 16 + wv * 4 + grp;
    int i = rowBlk + lr;
    float s0 = 0.f, s1 = 0.f, s2 = 0.f, s3 = 0.f, sd = 0.f;
    if (i < N) {
      int beg = rowptr[i], end = rowptr[i + 1];
      int e = beg;
#pragma unroll 1
      for (; e + 8 <= end; e += 8) {
        int ix[8];
#pragma unroll
        for (int u = 0; u < 8; u++) ix[u] = colx[e + u];
        uint2 v[8];
        float dd[8];
#pragma unroll
        for (int u = 0; u < 8; u++) { v[u] = xs[(size_t)ix[u] * 16 + l16]; dd[u] = dinv[ix[u]]; }
#pragma unroll
        for (int u = 0; u < 8; u++) {
          float2 a = unpack2(v[u].x), b = unpack2(v[u].y);
          s0 += a.x; s1 += a.y; s2 += b.x; s3 += b.y;
          sd += dd[u];
        }
      }
#pragma unroll 1
      for (; e < end; e++) {
        int sr = colx[e];
        uint2 vv = xs[(size_t)sr * 16 + l16];
        float2 a = unpack2(vv.x), b = unpack2(vv.y);
        s0 += a.x; s1 += a.y; s2 += b.x; s3 += b.y;
        sd += dinv[sr];
      }
    }
    float di = (i < N) ? dinv[i] : 0.f;
    *(uint2*)&Al[lr * KP + l16 * 4] =
        make_uint2(pack2(s0 * di, s1 * di), pack2(s2 * di, s3 * di));
    if (l16 == 0) wvl[lr] = di * sd;
  }
  __syncthreads();

  int l15 = lane & 15;
  int kg = lane >> 4;
  int wr = wv & 1, wc = wv >> 1;
  f16x8 af[2];
#pragma unroll
  for (int j = 0; j < 2; j++)
    af[j] = *(const f16x8*)&Al[(wr * 16 + l15) * KP + kg * 8 + j * 32];

  f32x4 acc[4];
#pragma unroll
  for (int t = 0; t < 4; t++) acc[t] = {0.f, 0.f, 0.f, 0.f};
#pragma unroll
  for (int j = 0; j < 2; j++) {
#pragma unroll
    for (int t = 0; t < 4; t++) {
      f16x8 bf = *(const f16x8*)&MT[(size_t)(wc * 64 + t * 16 + l15) * 64 + kg * 8 + j * 32];
      acc[t] = __builtin_amdgcn_mfma_f32_16x16x32_f16(af[j], bf, acc[t], 0, 0, 0);
    }
  }

  int rbaseL = wr * 16 + kg * 4;
  int rbase = rowBlk + rbaseL;
  float wrow[4];
#pragma unroll
  for (int r = 0; r < 4; r++) wrow[r] = wvl[rbaseL + r];

#pragma unroll
  for (int t = 0; t < 4; t++) {
    int ch = wc * 64 + t * 16 + l15;
    float bb = bias[ch];
    float b2v = bias2[ch];
    float s = 0.f, q = 0.f;
#pragma unroll
    for (int r = 0; r < 4; r++) {
      int row = rbase + r;
      if (row < N) {
        float o = fmaf(wrow[r], b2v, acc[t][r] + bb);
        __half oh = __float2half(o);
        Yh[(size_t)row * 128 + ch] = *(unsigned short*)&oh;
        s += o;
        q += o * o;
      }
    }
    s += __shfl_xor(s, 16); s += __shfl_xor(s, 32);
    q += __shfl_xor(q, 16); q += __shfl_xor(q, 32);
    if (kg == 0) { red[wr][0][ch] = s; red[wr][1][ch] = q; }
  }
  __syncthreads();
  int st = threadIdx.x >> 7, ch2 = threadIdx.x & 127;
  float v = red[0][st][ch2] + red[1][st][ch2];
  atomicAdd(&stat[(blockIdx.x & 7) * 256 + st * 128 + ch2], v);
}

// ---- fused prep1 + agg1 + gemm1: 32-row tiles, 8-deep gather (R13) ----
__global__ __launch_bounds__(256, 4) void k_aggemm1(
    const unsigned short* __restrict__ Hprev,  // N x 128 fp16
    const int* __restrict__ rowptr, const int* __restrict__ colx,
    const float* __restrict__ dinv,
    const unsigned short* __restrict__ WT,     // 128 x 128 fp16 (n-major)
    const float* __restrict__ statPrev, const float* __restrict__ gamma,
    const float* __restrict__ beta, float invN,
    const float* __restrict__ bias,            // bc[l]
    float* __restrict__ statCur, unsigned short* __restrict__ Yh, int N) {
  constexpr int KP = 136;                      // +8 fp16 pad
  __shared__ unsigned short Al[32 * KP];
  __shared__ float scsh[256];
  __shared__ float red[2][2][128];

  if (threadIdx.x < 128) {
    int c = threadIdx.x;
    float ss = 0.f, qs = 0.f;
#pragma unroll
    for (int r = 0; r < 8; r++) {
      ss += statPrev[r * 256 + c];
      qs += statPrev[r * 256 + 128 + c];
    }
    float mu = ss * invN;
    float var = qs * invN - mu * mu;
    float sc = rsqrtf(var + 1e-5f) * gamma[c];
    scsh[c] = sc;
    scsh[128 + c] = beta[c] - mu * sc;
  }
  __syncthreads();

  int lane = threadIdx.x & 63;
  int wv = threadIdx.x >> 6;
  int half = lane >> 5, l32 = lane & 31;
  int rowBlk = blockIdx.x * 32;
  const uint2* Hp = (const uint2*)Hprev;
  float4 sc = ((const float4*)scsh)[l32];
  float4 sh = ((const float4*)(scsh + 128))[l32];

#pragma unroll 1
  for (int it = 0; it < 4; it++) {
    int lr = it * 8 + wv * 2 + half;
    int i = rowBlk + lr;
    float4 s = make_float4(0.f, 0.f, 0.f, 0.f);
    if (i < N) {
      int beg = rowptr[i], end = rowptr[i + 1];
      int e = beg;
#pragma unroll 1
      for (; e + 8 <= end; e += 8) {
        int ix[8];
#pragma unroll
        for (int u = 0; u < 8; u++) ix[u] = colx[e + u];
        uint2 v[8];
        float dd[8];
#pragma unroll
        for (int u = 0; u < 8; u++) { v[u] = Hp[(size_t)ix[u] * 32 + l32]; dd[u] = dinv[ix[u]]; }
#pragma unroll
        for (int u = 0; u < 8; u++) {
          float2 a = unpack2(v[u].x), b = unpack2(v[u].y);
          s.x += fmaxf(fmaf(a.x, sc.x, sh.x), 0.f) * dd[u];
          s.y += fmaxf(fmaf(a.y, sc.y, sh.y), 0.f) * dd[u];
          s.z += fmaxf(fmaf(b.x, sc.z, sh.z), 0.f) * dd[u];
          s.w += fmaxf(fmaf(b.y, sc.w, sh.w), 0.f) * dd[u];
        }
      }
#pragma unroll 1
      for (; e < end; e++) {
        int sr = colx[e];
        uint2 vv = Hp[(size_t)sr * 32 + l32];
        float dsr = dinv[sr];
        float2 a = unpack2(vv.x), b = unpack2(vv.y);
        s.x += fmaxf(fmaf(a.x, sc.x, sh.x), 0.f) * dsr;
        s.y += fmaxf(fmaf(a.y, sc.y, sh.y), 0.f) * dsr;
        s.z += fmaxf(fmaf(b.x, sc.z, sh.z), 0.f) * dsr;
        s.w += fmaxf(fmaf(b.y, sc.w, sh.w), 0.f) * dsr;
      }
    }
    float di = (i < N) ? dinv[i] : 0.f;
    *(uint2*)&Al[lr * KP + l32 * 4] =
        make_uint2(pack2(s.x * di, s.y * di), pack2(s.z * di, s.w * di));
  }
  __syncthreads();

  int l15 = lane & 15;
  int kg = lane >> 4;
  int wr = wv & 1, wc = wv >> 1;
  f16x8 af[4];
#pragma unroll
  for (int j = 0; j < 4; j++)
    af[j] = *(const f16x8*)&Al[(wr * 16 + l15) * KP + kg * 8 + j * 32];

  f32x4 acc[4];
#pragma unroll
  for (int t = 0; t < 4; t++) acc[t] = {0.f, 0.f, 0.f, 0.f};
#pragma unroll
  for (int j = 0; j < 4; j++) {
#pragma unroll
    for (int t = 0; t < 4; t++) {
      f16x8 bf = *(const f16x8*)&WT[(size_t)(wc * 64 + t * 16 + l15) * 128 + kg * 8 + j * 32];
      acc[t] = __builtin_amdgcn_mfma_f32_16x16x32_f16(af[j], bf, acc[t], 0, 0, 0);
    }
  }

  int rbase = rowBlk + wr * 16 + kg * 4;
#pragma unroll
  for (int t = 0; t < 4; t++) {
    int ch = wc * 64 + t * 16 + l15;
    float bb = bias[ch];
    float s = 0.f, q = 0.f;
#pragma unroll
    for (int r = 0; r < 4; r++) {
      int row = rbase + r;
      if (row < N) {
        float o = acc[t][r] + bb;
        __half oh = __float2half(o);
        Yh[(size_t)row * 128 + ch] = *(unsigned short*)&oh;
        s += o;
        q += o * o;
      }
    }
    s += __shfl_xor(s, 16); s += __shfl_xor(s, 32);
    q += __shfl_xor(q, 16); q += __shfl_xor(q, 32);
    if (kg == 0) { red[wr][0][ch] = s; red[wr][1][ch] = q; }
  }
  __syncthreads();
  int st = threadIdx.x >> 7, ch2 = threadIdx.x & 127;
  float v = red[0][st][ch2] + red[1][st][ch2];
  atomicAdd(&statCur[(blockIdx.x & 7) * 256 + st * 128 + ch2], v);
}

// ---- standalone W transpose (only layers l>=2) ----
__global__ __launch_bounds__(256) void k_wprep(const float* __restrict__ Wsrc,
                                               unsigned short* __restrict__ WT) {
  int i = blockIdx.x * 256 + threadIdx.x;
  int n = i & 127, k = i >> 7;
  ((__half*)WT)[(size_t)n * 128 + k] = __float2half(Wsrc[i]);
}

// ---- Pool: BN inline + ReLU + segment sum. 512 blocks, half2 loads (R10) ----
__global__ __launch_bounds__(256) void k_pool(
    const unsigned* __restrict__ H16u,       // N x 64 half2-pairs
    const float* __restrict__ stat, const float* __restrict__ gamma,
    const float* __restrict__ beta, float invN,
    const int* __restrict__ gstart, float* __restrict__ pooled) {
  __shared__ float scsh[256];
  __shared__ float red[4][128];
  if (threadIdx.x < 128) {
    int c = threadIdx.x;
    float ss = 0.f, qs = 0.f;
#pragma unroll
    for (int r = 0; r < 8; r++) {
      ss += stat[r * 256 + c];
      qs += stat[r * 256 + 128 + c];
    }
    float mu = ss * invN;
    float var = qs * invN - mu * mu;
    float sc = rsqrtf(var + 1e-5f) * gamma[c];
    scsh[c] = sc;
    scsh[128 + c] = beta[c] - mu * sc;
  }
  __syncthreads();

  int g = blockIdx.x >> 3;
  int part = blockIdx.x & 7;
  int beg = gstart[g], end = gstart[g + 1];
  int len = end - beg;
  int p0 = beg + (len * part) / 8;
  int p1 = beg + (len * (part + 1)) / 8;

  int l64 = threadIdx.x & 63;      // channel pair
  int rs = threadIdx.x >> 6;       // 0..3 row substream
  int c0 = l64 * 2;
  float sc0 = scsh[c0], sc1 = scsh[c0 + 1];
  float sh0 = scsh[128 + c0], sh1 = scsh[128 + c0 + 1];
  int plen = p1 - p0;
  int q0 = p0 + (plen * rs) / 4;
  int q1 = p0 + (plen * (rs + 1)) / 4;

  float a0 = 0.f, a1 = 0.f;
  for (int r = q0; r < q1; r++) {
    float2 f = unpack2(H16u[(size_t)r * 64 + l64]);
    a0 += fmaxf(fmaf(f.x, sc0, sh0), 0.f);
    a1 += fmaxf(fmaf(f.y, sc1, sh1), 0.f);
  }
  red[rs][c0] = a0;
  red[rs][c0 + 1] = a1;
  __syncthreads();
  if (threadIdx.x < 128) {
    float s = red[0][threadIdx.x] + red[1][threadIdx.x] +
              red[2][threadIdx.x] + red[3][threadIdx.x];
    atomicAdd(&pooled[g * 128 + threadIdx.x], s);
  }
}

// ---- Head MLP (1 block) ----
__global__ __launch_bounds__(256) void k_mlp(const float* __restrict__ pooled,
                                             const int* __restrict__ gstart,
                                             const float* __restrict__ W1,
                                             const float* __restrict__ b1,
                                             const float* __restrict__ W2,
                                             const float* __restrict__ b2,
                                             float* __restrict__ out) {
  __shared__ float P[64 * 128];
  __shared__ float Z[64 * 64];
  for (int i = threadIdx.x; i < 64 * 128; i += 256) {
    int g = i >> 7;
    int cnt = gstart[g + 1] - gstart[g];
    P[i] = pooled[i] / (float)(cnt > 1 ? cnt : 1);
  }
  __syncthreads();
  for (int i = threadIdx.x; i < 64 * 64; i += 256) {
    int g = i >> 6, m = i & 63;
    float acc = b1[m];
    for (int k = 0; k < 128; k++) acc += P[(g << 7) + k] * W1[k * 64 + m];
    Z[i] = fmaxf(acc, 0.f);
  }
  __syncthreads();
  if (threadIdx.x < 64) {
    int g = threadIdx.x;
    float acc = b2[0];
    for (int m = 0; m < 64; m++) acc += Z[(g << 6) + m] * W2[m];
    out[g] = 1.f / (1.f + expf(-acc));
  }
}

// ---------------------------------------------------------------------------

extern "C" void kernel_launch(void* const* d_in, const int* in_sizes, int n_in,
                              void* d_out, int out_size, void* d_ws, size_t ws_size,
                              hipStream_t stream) {
  const float* x      = (const float*)d_in[0];
  const int*   ei     = (const int*)d_in[1];
  const int*   batch  = (const int*)d_in[2];
  const float* W_enc  = (const float*)d_in[3];
  const float* b_enc  = (const float*)d_in[4];
  const float* Wc     = (const float*)d_in[5];
  const float* bc     = (const float*)d_in[6];
  const float* gamma  = (const float*)d_in[7];
  const float* beta   = (const float*)d_in[8];
  const float* W1     = (const float*)d_in[9];
  const float* b1     = (const float*)d_in[10];
  const float* W2     = (const float*)d_in[11];
  const float* b2     = (const float*)d_in[12];
  float* out = (float*)d_out;

  const int N = in_sizes[2];         // 50000
  const int E = in_sizes[1] / 2;     // 500000
  const int NL = in_sizes[6] / 128;  // 2 layers

  size_t off = 0;
  auto alloc = [&](size_t bytes) {
    void* p = (char*)d_ws + off;
    off += (bytes + 255) & ~(size_t)255;
    return p;
  };
  unsigned short* h16a = (unsigned short*)alloc((size_t)N * 128 * 2);
  unsigned short* h16b = (unsigned short*)alloc((size_t)N * 128 * 2);
  int*   deg    = (int*)alloc((size_t)N * 4);
  float* dinv   = (float*)alloc((size_t)N * 4);
  int*   rowptr = (int*)alloc((size_t)(N + 1) * 4);
  int*   cursor = (int*)alloc((size_t)N * 4);
  int*   colx   = (int*)alloc((size_t)(E + N) * 4);
  int*   blksum = (int*)alloc(1024 * 4);
  float* bnstat = (float*)alloc((size_t)NL * 2048 * 4);  // NL x 8 reps x 256
  float* pooled = (float*)alloc(64 * 128 * 4);
  int*   gstart = (int*)alloc(65 * 4);
  unsigned short* MT  = (unsigned short*)alloc(128 * 64 * 2);
  unsigned short* WT1 = (unsigned short*)alloc(128 * 128 * 2);
  float* bfold  = (float*)alloc(128 * 4);
  unsigned* xs  = (unsigned*)alloc((size_t)N * 64 * 2);

  int nbN = (N + 255) / 256;
  int nbEN = (E + N + 255) / 256;
  float invN = 1.f / (float)N;
  int tiles32 = (N + 31) / 32;

  k_setup<<<nbN + 130, 256, 0, stream>>>(
      deg, bnstat, NL * 2048, pooled, N, nbN, W_enc, b_enc, Wc, MT, bfold, NL,
      Wc + (size_t)128 * 128, WT1, batch, gstart);
  k_deg<<<(E + 255) / 256, 256, 0, stream>>>(ei, E, deg);
  k_scan_a<<<nbN, 256, 0, stream>>>(deg, N, rowptr, blksum);
  k_scan_c<<<nbN, 256, 0, stream>>>(deg, N, E + N, blksum, rowptr, cursor, dinv);
  k_fillprep<<<nbEN + (N * 16 + 255) / 256, 256, 0, stream>>>(
      ei, E, N, nbEN, cursor, colx, x, dinv, xs);

  // ---- layer 0: fused agg + GEMM (encoder folded) ----
  k_aggemm0<<<tiles32, 256, 0, stream>>>((const uint2*)xs, rowptr, colx, dinv,
                                         MT, bc, bfold, bnstat, h16a, N);

  // ---- layers 1..NL-1: fused BN+ReLU-gather + agg + GEMM ----
  unsigned short* cur = h16a;
  unsigned short* nxt = h16b;
  for (int l = 1; l < NL; l++) {
    if (l > 1)   // WT1 for l==1 comes from k_setup
      k_wprep<<<64, 256, 0, stream>>>(Wc + (size_t)l * 128 * 128, WT1);
    k_aggemm1<<<tiles32, 256, 0, stream>>>(
        cur, rowptr, colx, dinv, WT1, bnstat + (l - 1) * 2048,
        gamma + (l - 1) * 128, beta + (l - 1) * 128, invN, bc + l * 128,
        bnstat + l * 2048, nxt, N);
    unsigned short* tmp = cur; cur = nxt; nxt = tmp;
  }

  k_pool<<<64 * 8, 256, 0, stream>>>((const unsigned*)cur,
                                     bnstat + (NL - 1) * 2048,
                                     gamma + (NL - 1) * 128,
                                     beta + (NL - 1) * 128, invN, gstart,
                                     pooled);
  k_mlp<<<1, 256, 0, stream>>>(pooled, gstart, W1, b1, W2, b2, out);
}